// Round 2
// baseline (191.551 us; speedup 1.0000x reference)
//
#include <hip/hip_runtime.h>
#include <hip/hip_bf16.h>

#define B_ 256
#define S_ 256
#define T_ 128
#define START_ 126
#define STOP_ 127

typedef __attribute__((ext_vector_type(8))) short short8;
typedef __attribute__((ext_vector_type(4))) float f32x4;
typedef __attribute__((ext_vector_type(4))) int i32x4;

// float -> bf16 bits, round-to-nearest-even
__device__ __forceinline__ unsigned short f2bf(float f) {
    unsigned u = __float_as_uint(f);
    unsigned r = (u + 0x7FFFu + ((u >> 16) & 1u)) >> 16;
    return (unsigned short)r;
}

// One wave (64 threads) per sequence. Everything wave-synchronous:
// no __syncthreads, no LDS buffers. ep lives in 2 regs/lane (u0=u[l],
// u1=u[64+l]); redistribution to MFMA A-fragments via ds_bpermute with a
// custom shared A/B k-map (any k-permutation cancels as long as A and B
// use the same map — validated empirically in round 1).
__global__ __launch_bounds__(64, 1) void crf_fwd(
    const float* __restrict__ feats,      // [B, S, T]
    const float* __restrict__ trans,      // [T, T]
    const int*   __restrict__ tags,       // [B, S]
    const int*   __restrict__ mask,       // [B, S]
    float* __restrict__ out)              // [1]
{
    const int b = blockIdx.x;
    const int l = threadIdx.x;            // 0..63
    const int g = l >> 4;                 // 16-lane group
    const int c = l & 15;

    const float* fb = feats + (size_t)b * (S_ * T_);

    // ---- B fragments: et = exp(trans), loaded with the lambda k-map:
    //      element e=2q+h of (kt, lane) holds k = kt*16 + 4g + q + 64h ----
    short8 bfrag[4][8];
    #pragma unroll
    for (int kt = 0; kt < 4; ++kt) {
        #pragma unroll
        for (int nt = 0; nt < 8; ++nt) {
            short8 f;
            #pragma unroll
            for (int e = 0; e < 8; ++e) {
                const int k = kt * 16 + 4 * g + (e >> 1) + 64 * (e & 1);
                f[e] = (short)f2bf(__expf(trans[k * T_ + nt * 16 + c]));
            }
            bfrag[kt][nt] = f;
        }
    }

    // ---- sequence length (prefix mask) ----
    int cnt = 0;
    #pragma unroll
    for (int s4 = 0; s4 < 4; ++s4) cnt += mask[b * S_ + s4 * 64 + l];
    #pragma unroll
    for (int o = 32; o; o >>= 1) cnt += __shfl_xor(cnt, o, 64);
    const int len = cnt;                  // >= 128 by construction

    // ---- feats rows 0..7 into registers (raw; exp at consume time) ----
    float cf[16], nf[16];
    #pragma unroll
    for (int r = 0; r < 8; ++r) {
        cf[2 * r]     = fb[r * T_ + l];
        cf[2 * r + 1] = fb[r * T_ + 64 + l];
    }

    // ---- init: ep_0[j] = exp(feat0[j] + trans[START][j]) ----
    float u0 = __expf(cf[0] + trans[START_ * T_ + l]);
    float u1 = __expf(cf[1] + trans[START_ * T_ + 64 + l]);
    float M = 0.f;

    // ---- main recurrence ----
    for (int blk = 0; blk < 32; ++blk) {
        // prefetch next 8 feat rows (consumed ~8 steps later)
        if (blk + 1 < 32) {
            #pragma unroll
            for (int r = 0; r < 8; ++r) {
                nf[2 * r]     = fb[((blk + 1) * 8 + r) * T_ + l];
                nf[2 * r + 1] = fb[((blk + 1) * 8 + r) * T_ + 64 + l];
            }
        }
        #pragma unroll
        for (int r = 0; r < 8; ++r) {
            const int tt = blk * 8 + r;
            if (r == 0 && blk == 0) continue;   // t starts at 1
            if (tt >= len) goto done;
            {
                // --- distribute ep: one packed pair per source lane ---
                unsigned pk;
                asm("v_cvt_pk_bf16_f32 %0, %1, %2" : "=v"(pk) : "v"(u0), "v"(u1));
                i32x4 w[4];
                #pragma unroll
                for (int kt = 0; kt < 4; ++kt) {
                    #pragma unroll
                    for (int q = 0; q < 4; ++q) {
                        // source lane s = kt*16 + 4g + q holds (u[s], u[64+s])
                        w[kt][q] = __builtin_amdgcn_ds_bpermute(
                            64 * kt + 16 * g + 4 * q, (int)pk);
                    }
                }
                // --- 32 MFMAs: 8 independent acc chains, kt-outer ---
                f32x4 acc[8];
                #pragma unroll
                for (int n = 0; n < 8; ++n) acc[n] = (f32x4){0.f, 0.f, 0.f, 0.f};
                #pragma unroll
                for (int kt = 0; kt < 4; ++kt) {
                    const short8 a = *(const short8*)&w[kt];
                    #pragma unroll
                    for (int n = 0; n < 8; ++n)
                        acc[n] = __builtin_amdgcn_mfma_f32_16x16x32_bf16(
                            a, bfrag[kt][n], acc[n], 0, 0, 0);
                }
                // --- select this lane's outputs: j0=l (nt=g), j1=64+l (nt=4+g) ---
                float lo0 = (g & 1) ? acc[1][0] : acc[0][0];
                float hi0 = (g & 1) ? acc[3][0] : acc[2][0];
                float v0  = (g & 2) ? hi0 : lo0;
                float lo1 = (g & 1) ? acc[5][0] : acc[4][0];
                float hi1 = (g & 1) ? acc[7][0] : acc[6][0];
                float v1  = (g & 2) ? hi1 : lo1;
                u0 = v0 * __expf(cf[2 * r]);
                u1 = v1 * __expf(cf[2 * r + 1]);
                // --- wave-local renorm via representative scale, every 4 steps ---
                if ((tt & 3) == 0) {
                    const float sc = __shfl(u0, 0, 64);
                    const float rs = 1.0f / sc;
                    u0 *= rs;
                    u1 *= rs;
                    M += __logf(sc);
                }
            }
        }
        if (blk + 1 < 32) {
            #pragma unroll
            for (int i = 0; i < 16; ++i) cf[i] = nf[i];
        }
    }
done: ;

    // ---- forward score: M + log(sum_i ep_i * exp(trans[i][STOP])) ----
    float v = u0 * __expf(trans[l * T_ + STOP_])
            + u1 * __expf(trans[(64 + l) * T_ + STOP_]);
    #pragma unroll
    for (int o = 32; o; o >>= 1) v += __shfl_xor(v, o, 64);
    const float fwd = M + __logf(v);

    // ---- gold path score ----
    float gg = 0.f;
    #pragma unroll
    for (int s4 = 0; s4 < 4; ++s4) {
        const int s = s4 * 64 + l;
        if (mask[b * S_ + s]) {
            const int tg = tags[b * S_ + s];
            const int pv = (s == 0) ? START_ : tags[b * S_ + s - 1];
            gg += fb[s * T_ + tg] + trans[pv * T_ + tg];
            if (s == len - 1) gg += trans[tg * T_ + STOP_];
        }
    }
    #pragma unroll
    for (int o = 32; o; o >>= 1) gg += __shfl_xor(gg, o, 64);

    if (l == 0) atomicAdd(out, fwd - gg);
}

extern "C" void kernel_launch(void* const* d_in, const int* in_sizes, int n_in,
                              void* d_out, int out_size, void* d_ws, size_t ws_size,
                              hipStream_t stream) {
    const float* feats = (const float*)d_in[0];
    const float* trans = (const float*)d_in[1];
    const int*   tags  = (const int*)d_in[2];
    const int*   mask  = (const int*)d_in[3];
    float* out = (float*)d_out;

    hipMemsetAsync(out, 0, sizeof(float), stream);
    crf_fwd<<<dim3(B_), dim3(64), 0, stream>>>(feats, trans, tags, mask, out);
}